// Round 1
// baseline (125.175 us; speedup 1.0000x reference)
//
#include <hip/hip_runtime.h>

#define NPIX (16 * 768 * 768)   // 9437184 pixels per map
#define NVEC (NPIX / 4)         // 2359296 float4 groups

// ws layout: [0]=sum_char_loss, [1]=cnt_char_pos, [2]=sum_aff_loss, [3]=cnt_aff_pos

__global__ __launch_bounds__(256) void craft_reduce(
    const float* __restrict__ out,   // [NPIX][2] interleaved (char, aff)
    const float* __restrict__ cmap,  // [NPIX]
    const float* __restrict__ amap,  // [NPIX]
    float* __restrict__ ws)
{
    const int tid = blockIdx.x * blockDim.x + threadIdx.x;
    const int nthreads = gridDim.x * blockDim.x;

    float sum_c = 0.f, cnt_c = 0.f, sum_a = 0.f, cnt_a = 0.f;

    const float4* out4  = reinterpret_cast<const float4*>(out);
    const float4* cmap4 = reinterpret_cast<const float4*>(cmap);
    const float4* amap4 = reinterpret_cast<const float4*>(amap);

    for (int v = tid; v < NVEC; v += nthreads) {
        float4 o0 = out4[2 * v];       // pixels 4v, 4v+1 : (c,a,c,a)
        float4 o1 = out4[2 * v + 1];   // pixels 4v+2, 4v+3
        float4 ct = cmap4[v];
        float4 at = amap4[v];

        float cp[4]  = {o0.x, o0.z, o1.x, o1.z};
        float ap[4]  = {o0.y, o0.w, o1.y, o1.w};
        float ctv[4] = {ct.x, ct.y, ct.z, ct.w};
        float atv[4] = {at.x, at.y, at.z, at.w};

        #pragma unroll
        for (int j = 0; j < 4; ++j) {
            float t = ctv[j];
            float d = cp[j] - t;
            bool pos = (t >= 0.1f);
            bool neg = (t <= 0.0f);
            sum_c += (pos || neg) ? d * d : 0.f;
            cnt_c += pos ? 1.f : 0.f;

            t = atv[j];
            d = ap[j] - t;
            pos = (t >= 0.1f);
            neg = (t <= 0.0f);
            sum_a += (pos || neg) ? d * d : 0.f;
            cnt_a += pos ? 1.f : 0.f;
        }
    }

    // wave(64) butterfly-free down-reduce
    #pragma unroll
    for (int off = 32; off > 0; off >>= 1) {
        sum_c += __shfl_down(sum_c, off, 64);
        cnt_c += __shfl_down(cnt_c, off, 64);
        sum_a += __shfl_down(sum_a, off, 64);
        cnt_a += __shfl_down(cnt_a, off, 64);
    }

    __shared__ float red[4][4];
    const int wave = threadIdx.x >> 6;
    const int lane = threadIdx.x & 63;
    if (lane == 0) {
        red[wave][0] = sum_c;
        red[wave][1] = cnt_c;
        red[wave][2] = sum_a;
        red[wave][3] = cnt_a;
    }
    __syncthreads();

    if (threadIdx.x == 0) {
        float s0 = 0.f, s1 = 0.f, s2 = 0.f, s3 = 0.f;
        #pragma unroll
        for (int w = 0; w < 4; ++w) {
            s0 += red[w][0];
            s1 += red[w][1];
            s2 += red[w][2];
            s3 += red[w][3];
        }
        atomicAdd(&ws[0], s0);
        atomicAdd(&ws[1], s1);
        atomicAdd(&ws[2], s2);
        atomicAdd(&ws[3], s3);
    }
}

__global__ void craft_final(const float* __restrict__ ws, float* __restrict__ out)
{
    const float n = (float)NPIX;
    float lc = ws[0] / (ws[1] + n);
    float la = ws[2] / (ws[3] + n);
    out[0] = (2.f * lc + la) * 100.f;
}

extern "C" void kernel_launch(void* const* d_in, const int* in_sizes, int n_in,
                              void* d_out, int out_size, void* d_ws, size_t ws_size,
                              hipStream_t stream)
{
    const float* out_pred = (const float*)d_in[0];  // (16,768,768,2)
    const float* cmap     = (const float*)d_in[1];  // (16,768,768)
    const float* amap     = (const float*)d_in[2];  // (16,768,768)
    float* result = (float*)d_out;
    float* ws     = (float*)d_ws;

    hipMemsetAsync(ws, 0, 4 * sizeof(float), stream);

    dim3 grid(2048), block(256);
    craft_reduce<<<grid, block, 0, stream>>>(out_pred, cmap, amap, ws);
    craft_final<<<1, 1, 0, stream>>>(ws, result);
}

// Round 2
// 123.566 us; speedup vs baseline: 1.0130x; 1.0130x over previous
//
#include <hip/hip_runtime.h>

#define NPIX  (16 * 768 * 768)   // 9437184 pixels per map
#define NUNIT (NPIX / 2)         // 4718592 units; 1 unit = 2 pixels
#define NTHREADS (2048 * 256)    // 524288
#define UPT   (NUNIT / NTHREADS) // 9 units per thread, exact

// ws layout: [0]=sum_char_loss, [1]=cnt_char_pos, [2]=sum_aff_loss, [3]=cnt_aff_pos

__global__ __launch_bounds__(256, 4) void craft_reduce(
    const float* __restrict__ out,   // [NPIX][2] interleaved (char, aff)
    const float* __restrict__ cmap,  // [NPIX]
    const float* __restrict__ amap,  // [NPIX]
    float* __restrict__ ws)
{
    const int tid = blockIdx.x * blockDim.x + threadIdx.x;

    const float4* out4  = reinterpret_cast<const float4*>(out);   // unit u -> pixels 2u,2u+1
    const float2* cmap2 = reinterpret_cast<const float2*>(cmap);
    const float2* amap2 = reinterpret_cast<const float2*>(amap);

    // Hoist ALL loads: 9 x (float4 + float2 + float2) = 27 VMEM instrs in flight.
    float4 o[UPT];
    float2 ct[UPT], at[UPT];
    #pragma unroll
    for (int k = 0; k < UPT; ++k) {
        const int u = tid + k * NTHREADS;   // lane-consecutive within each step
        o[k]  = out4[u];
        ct[k] = cmap2[u];
        at[k] = amap2[u];
    }

    float sum_c = 0.f, cnt_c = 0.f, sum_a = 0.f, cnt_a = 0.f;

    #pragma unroll
    for (int k = 0; k < UPT; ++k) {
        // pixel 0 of unit: (o.x=char, o.y=aff), targets ct.x / at.x
        {
            float t = ct[k].x;
            float d = o[k].x - t;
            sum_c += (t >= 0.1f || t <= 0.0f) ? d * d : 0.f;
            cnt_c += (t >= 0.1f) ? 1.f : 0.f;

            t = at[k].x;
            d = o[k].y - t;
            sum_a += (t >= 0.1f || t <= 0.0f) ? d * d : 0.f;
            cnt_a += (t >= 0.1f) ? 1.f : 0.f;
        }
        // pixel 1 of unit: (o.z=char, o.w=aff), targets ct.y / at.y
        {
            float t = ct[k].y;
            float d = o[k].z - t;
            sum_c += (t >= 0.1f || t <= 0.0f) ? d * d : 0.f;
            cnt_c += (t >= 0.1f) ? 1.f : 0.f;

            t = at[k].y;
            d = o[k].w - t;
            sum_a += (t >= 0.1f || t <= 0.0f) ? d * d : 0.f;
            cnt_a += (t >= 0.1f) ? 1.f : 0.f;
        }
    }

    // wave(64) down-reduce
    #pragma unroll
    for (int off = 32; off > 0; off >>= 1) {
        sum_c += __shfl_down(sum_c, off, 64);
        cnt_c += __shfl_down(cnt_c, off, 64);
        sum_a += __shfl_down(sum_a, off, 64);
        cnt_a += __shfl_down(cnt_a, off, 64);
    }

    __shared__ float red[4][4];
    const int wave = threadIdx.x >> 6;
    const int lane = threadIdx.x & 63;
    if (lane == 0) {
        red[wave][0] = sum_c;
        red[wave][1] = cnt_c;
        red[wave][2] = sum_a;
        red[wave][3] = cnt_a;
    }
    __syncthreads();

    if (threadIdx.x == 0) {
        float s0 = 0.f, s1 = 0.f, s2 = 0.f, s3 = 0.f;
        #pragma unroll
        for (int w = 0; w < 4; ++w) {
            s0 += red[w][0];
            s1 += red[w][1];
            s2 += red[w][2];
            s3 += red[w][3];
        }
        atomicAdd(&ws[0], s0);
        atomicAdd(&ws[1], s1);
        atomicAdd(&ws[2], s2);
        atomicAdd(&ws[3], s3);
    }
}

__global__ void craft_final(const float* __restrict__ ws, float* __restrict__ out)
{
    const float n = (float)NPIX;
    float lc = ws[0] / (ws[1] + n);
    float la = ws[2] / (ws[3] + n);
    out[0] = (2.f * lc + la) * 100.f;
}

extern "C" void kernel_launch(void* const* d_in, const int* in_sizes, int n_in,
                              void* d_out, int out_size, void* d_ws, size_t ws_size,
                              hipStream_t stream)
{
    const float* out_pred = (const float*)d_in[0];  // (16,768,768,2)
    const float* cmap     = (const float*)d_in[1];  // (16,768,768)
    const float* amap     = (const float*)d_in[2];  // (16,768,768)
    float* result = (float*)d_out;
    float* ws     = (float*)d_ws;

    hipMemsetAsync(ws, 0, 4 * sizeof(float), stream);

    craft_reduce<<<dim3(2048), dim3(256), 0, stream>>>(out_pred, cmap, amap, ws);
    craft_final<<<1, 1, 0, stream>>>(ws, result);
}

// Round 3
// 122.143 us; speedup vs baseline: 1.0248x; 1.0116x over previous
//
#include <hip/hip_runtime.h>

#define NPIX  (16 * 768 * 768)   // 9437184 pixels per map
#define NUNIT (NPIX / 2)         // 4718592 units; 1 unit = 2 pixels
#define NTHREADS (2048 * 256)    // 524288
#define UPT   (NUNIT / NTHREADS) // 9 units per thread, exact

// ws layout: [0]=sum_char_loss, [1]=cnt_char_pos, [2]=sum_aff_loss, [3]=cnt_aff_pos

__global__ __launch_bounds__(256, 4) void craft_reduce(
    const float* __restrict__ out,   // [NPIX][2] interleaved (char, aff)
    const float* __restrict__ cmap,  // [NPIX]
    const float* __restrict__ amap,  // [NPIX]
    float* __restrict__ ws)
{
    const int tid = blockIdx.x * blockDim.x + threadIdx.x;

    const float4* out4  = reinterpret_cast<const float4*>(out);   // unit u -> pixels 2u,2u+1
    const float2* cmap2 = reinterpret_cast<const float2*>(cmap);
    const float2* amap2 = reinterpret_cast<const float2*>(amap);

    // Hoist ALL loads: 9 x (float4 + float2 + float2) = 27 VMEM instrs in flight.
    float4 o[UPT];
    float2 ct[UPT], at[UPT];
    #pragma unroll
    for (int k = 0; k < UPT; ++k) {
        const int u = tid + k * NTHREADS;   // lane-consecutive within each step
        o[k]  = out4[u];
        ct[k] = cmap2[u];
        at[k] = amap2[u];
    }

    float sum_c = 0.f, cnt_c = 0.f, sum_a = 0.f, cnt_a = 0.f;

    #pragma unroll
    for (int k = 0; k < UPT; ++k) {
        // pixel 0 of unit: (o.x=char, o.y=aff), targets ct.x / at.x
        {
            float t = ct[k].x;
            float d = o[k].x - t;
            sum_c += (t >= 0.1f || t <= 0.0f) ? d * d : 0.f;
            cnt_c += (t >= 0.1f) ? 1.f : 0.f;

            t = at[k].x;
            d = o[k].y - t;
            sum_a += (t >= 0.1f || t <= 0.0f) ? d * d : 0.f;
            cnt_a += (t >= 0.1f) ? 1.f : 0.f;
        }
        // pixel 1 of unit: (o.z=char, o.w=aff), targets ct.y / at.y
        {
            float t = ct[k].y;
            float d = o[k].z - t;
            sum_c += (t >= 0.1f || t <= 0.0f) ? d * d : 0.f;
            cnt_c += (t >= 0.1f) ? 1.f : 0.f;

            t = at[k].y;
            d = o[k].w - t;
            sum_a += (t >= 0.1f || t <= 0.0f) ? d * d : 0.f;
            cnt_a += (t >= 0.1f) ? 1.f : 0.f;
        }
    }

    // wave(64) down-reduce
    #pragma unroll
    for (int off = 32; off > 0; off >>= 1) {
        sum_c += __shfl_down(sum_c, off, 64);
        cnt_c += __shfl_down(cnt_c, off, 64);
        sum_a += __shfl_down(sum_a, off, 64);
        cnt_a += __shfl_down(cnt_a, off, 64);
    }

    __shared__ float red[4][4];
    const int wave = threadIdx.x >> 6;
    const int lane = threadIdx.x & 63;
    if (lane == 0) {
        red[wave][0] = sum_c;
        red[wave][1] = cnt_c;
        red[wave][2] = sum_a;
        red[wave][3] = cnt_a;
    }
    __syncthreads();

    if (threadIdx.x == 0) {
        float s0 = 0.f, s1 = 0.f, s2 = 0.f, s3 = 0.f;
        #pragma unroll
        for (int w = 0; w < 4; ++w) {
            s0 += red[w][0];
            s1 += red[w][1];
            s2 += red[w][2];
            s3 += red[w][3];
        }
        atomicAdd(&ws[0], s0);
        atomicAdd(&ws[1], s1);
        atomicAdd(&ws[2], s2);
        atomicAdd(&ws[3], s3);
    }
}

__global__ void craft_final(const float* __restrict__ ws, float* __restrict__ out)
{
    const float n = (float)NPIX;
    float lc = ws[0] / (ws[1] + n);
    float la = ws[2] / (ws[3] + n);
    out[0] = (2.f * lc + la) * 100.f;
}

extern "C" void kernel_launch(void* const* d_in, const int* in_sizes, int n_in,
                              void* d_out, int out_size, void* d_ws, size_t ws_size,
                              hipStream_t stream)
{
    const float* out_pred = (const float*)d_in[0];  // (16,768,768,2)
    const float* cmap     = (const float*)d_in[1];  // (16,768,768)
    const float* amap     = (const float*)d_in[2];  // (16,768,768)
    float* result = (float*)d_out;
    float* ws     = (float*)d_ws;

    hipMemsetAsync(ws, 0, 4 * sizeof(float), stream);

    craft_reduce<<<dim3(2048), dim3(256), 0, stream>>>(out_pred, cmap, amap, ws);
    craft_final<<<1, 1, 0, stream>>>(ws, result);
}

// Round 4
// 121.191 us; speedup vs baseline: 1.0329x; 1.0079x over previous
//
#include <hip/hip_runtime.h>

#define NPIX  (16 * 768 * 768)   // 9437184 pixels per map
#define NUNIT (NPIX / 2)         // 4718592 units; 1 unit = 2 pixels
#define NTHREADS (2048 * 256)    // 524288
#define UPT   (NUNIT / NTHREADS) // 9 units per thread, exact

// ws layout: [0]=sum_char_loss, [1]=cnt_char_pos, [2]=sum_aff_loss, [3]=cnt_aff_pos

__global__ __launch_bounds__(256, 4) void craft_reduce(
    const float* __restrict__ out,   // [NPIX][2] interleaved (char, aff)
    const float* __restrict__ cmap,  // [NPIX]
    const float* __restrict__ amap,  // [NPIX]
    float* __restrict__ ws)
{
    const int tid = blockIdx.x * blockDim.x + threadIdx.x;

    const float4* out4  = reinterpret_cast<const float4*>(out);   // unit u -> pixels 2u,2u+1
    const float2* cmap2 = reinterpret_cast<const float2*>(cmap);
    const float2* amap2 = reinterpret_cast<const float2*>(amap);

    // Hoist ALL loads: 9 x (float4 + float2 + float2) = 27 VMEM instrs in flight.
    float4 o[UPT];
    float2 ct[UPT], at[UPT];
    #pragma unroll
    for (int k = 0; k < UPT; ++k) {
        const int u = tid + k * NTHREADS;   // lane-consecutive within each step
        o[k]  = out4[u];
        ct[k] = cmap2[u];
        at[k] = amap2[u];
    }

    float sum_c = 0.f, cnt_c = 0.f, sum_a = 0.f, cnt_a = 0.f;

    #pragma unroll
    for (int k = 0; k < UPT; ++k) {
        // pixel 0 of unit: (o.x=char, o.y=aff), targets ct.x / at.x
        {
            float t = ct[k].x;
            float d = o[k].x - t;
            sum_c += (t >= 0.1f || t <= 0.0f) ? d * d : 0.f;
            cnt_c += (t >= 0.1f) ? 1.f : 0.f;

            t = at[k].x;
            d = o[k].y - t;
            sum_a += (t >= 0.1f || t <= 0.0f) ? d * d : 0.f;
            cnt_a += (t >= 0.1f) ? 1.f : 0.f;
        }
        // pixel 1 of unit: (o.z=char, o.w=aff), targets ct.y / at.y
        {
            float t = ct[k].y;
            float d = o[k].z - t;
            sum_c += (t >= 0.1f || t <= 0.0f) ? d * d : 0.f;
            cnt_c += (t >= 0.1f) ? 1.f : 0.f;

            t = at[k].y;
            d = o[k].w - t;
            sum_a += (t >= 0.1f || t <= 0.0f) ? d * d : 0.f;
            cnt_a += (t >= 0.1f) ? 1.f : 0.f;
        }
    }

    // wave(64) down-reduce
    #pragma unroll
    for (int off = 32; off > 0; off >>= 1) {
        sum_c += __shfl_down(sum_c, off, 64);
        cnt_c += __shfl_down(cnt_c, off, 64);
        sum_a += __shfl_down(sum_a, off, 64);
        cnt_a += __shfl_down(cnt_a, off, 64);
    }

    __shared__ float red[4][4];
    const int wave = threadIdx.x >> 6;
    const int lane = threadIdx.x & 63;
    if (lane == 0) {
        red[wave][0] = sum_c;
        red[wave][1] = cnt_c;
        red[wave][2] = sum_a;
        red[wave][3] = cnt_a;
    }
    __syncthreads();

    if (threadIdx.x == 0) {
        float s0 = 0.f, s1 = 0.f, s2 = 0.f, s3 = 0.f;
        #pragma unroll
        for (int w = 0; w < 4; ++w) {
            s0 += red[w][0];
            s1 += red[w][1];
            s2 += red[w][2];
            s3 += red[w][3];
        }
        atomicAdd(&ws[0], s0);
        atomicAdd(&ws[1], s1);
        atomicAdd(&ws[2], s2);
        atomicAdd(&ws[3], s3);
    }
}

__global__ void craft_final(const float* __restrict__ ws, float* __restrict__ out)
{
    const float n = (float)NPIX;
    float lc = ws[0] / (ws[1] + n);
    float la = ws[2] / (ws[3] + n);
    out[0] = (2.f * lc + la) * 100.f;
}

extern "C" void kernel_launch(void* const* d_in, const int* in_sizes, int n_in,
                              void* d_out, int out_size, void* d_ws, size_t ws_size,
                              hipStream_t stream)
{
    const float* out_pred = (const float*)d_in[0];  // (16,768,768,2)
    const float* cmap     = (const float*)d_in[1];  // (16,768,768)
    const float* amap     = (const float*)d_in[2];  // (16,768,768)
    float* result = (float*)d_out;
    float* ws     = (float*)d_ws;

    hipMemsetAsync(ws, 0, 4 * sizeof(float), stream);

    craft_reduce<<<dim3(2048), dim3(256), 0, stream>>>(out_pred, cmap, amap, ws);
    craft_final<<<1, 1, 0, stream>>>(ws, result);
}